// Round 5
// baseline (1234.769 us; speedup 1.0000x reference)
//
#include <hip/hip_runtime.h>
#include <hip/hip_fp16.h>
#include <math.h>

// Fused multi-kernel resonator decoder for MI355X (gfx950).
// Per iteration only TWO kernels:
//   k_wexp  : W = exp2(c2 * sum of 256 fp16 partials)   (unnormalized softmax;
//             atan2 direction is scale-invariant, Z cancels)
//   k_fused : per 32-row T1 slice: re/im = W . T1 (DPP wave reduce) ->
//             normalize est in LDS (cos=re/|z|, sin=im/|z|, no atan2) ->
//             IMMEDIATELY compute this slice's partial sims for the NEXT
//             iteration from the L2-hot T1 rows -> fp16 partial store.
// T1[row=d*2+cs][k] is bf16 (16 MB, L3-resident, k-contiguous = coalesced
// everywhere). Total ws ~21 MB. No atomics, no memsets, no barriers.

#define KCODES 1024
#define DIMS   4096
#define BATCH  8
#define NITER_MAX 50          // device-side guard handles *nit_p < NITER_MAX
#define NSLICE 256            // partial-sims slices (16 dims each)

// ws layout (float offsets)
#define T1_SZF   (DIMS * 2 * KCODES / 2)       // bf16: 8M ushort = 4,194,304 f
#define EST_OFF  (T1_SZF)
#define EST_SZ   (DIMS * 2 * BATCH)            // est[row][b] f32 (one-time)
#define W_OFF    (EST_OFF + EST_SZ)
#define W_SZ     (BATCH * KCODES)
#define P_OFF    (W_OFF + W_SZ)                // fp16 partials [ds][b][k]

// ---- bf16 helpers ----
__device__ __forceinline__ ushort f2bf(float x) {
  unsigned u = __float_as_uint(x);
  return (ushort)((u + 0x7FFFu + ((u >> 16) & 1u)) >> 16);   // RNE
}
__device__ __forceinline__ float bf2f(ushort u) {
  return __uint_as_float(((unsigned)u) << 16);
}

// ---- DPP wave64 sum: result valid in lane 63 ----
template <int CTRL>
__device__ __forceinline__ float dpp_add(float x) {
  int v = __builtin_amdgcn_update_dpp(0, __float_as_int(x), CTRL, 0xF, 0xF, false);
  return x + __int_as_float(v);
}
__device__ __forceinline__ float wave_sum64(float x) {
  x = dpp_add<0x111>(x);
  x = dpp_add<0x112>(x);
  x = dpp_add<0x114>(x);
  x = dpp_add<0x118>(x);
  x = dpp_add<0x142>(x);   // row_bcast:15
  x = dpp_add<0x143>(x);   // row_bcast:31
  return x;
}

// ---- one-time: codebook angles -> bf16 T1[(d*2+cs)][k] via LDS transpose ----
__global__ __launch_bounds__(256) void k_trig(const float* __restrict__ cb,
                                              float* __restrict__ ws) {
  __shared__ float lc[64][65], ls[64][65];
  const int t  = threadIdx.x;
  const int bk = blockIdx.x & 15;        // 16 k-tiles
  const int bd = blockIdx.x >> 4;        // 64 d-tiles
  const int k0 = bk * 64, d0 = bd * 64;
  const int c = t & 63;
  #pragma unroll
  for (int i = 0; i < 16; ++i) {
    const int r = (t >> 6) + i * 4;
    float a = cb[(size_t)(k0 + r) * DIMS + d0 + c];
    float s, cc; sincosf(a, &s, &cc);
    lc[r][c] = cc; ls[r][c] = s;
  }
  __syncthreads();
  ushort* T1 = (ushort*)ws;
  #pragma unroll
  for (int j = 0; j < 16; ++j) {
    const int dd = (t >> 6) + j * 4;
    T1[(size_t)((d0 + dd) * 2 + 0) * KCODES + k0 + c] = f2bf(lc[c][dd]);
    T1[(size_t)((d0 + dd) * 2 + 1) * KCODES + k0 + c] = f2bf(ls[c][dd]);
  }
}

// ---- one-time: est init from superposed (f32, only read by k_sims0) ----
__global__ __launch_bounds__(256) void k_init(const float* __restrict__ sup,
                                              float* __restrict__ ws) {
  float* EST = ws + EST_OFF;
  const int i = blockIdx.x * 256 + threadIdx.x;   // 0..32767
  const int b = i >> 12, d = i & 4095;
  float s, c; sincosf(sup[(size_t)b * DIMS + d], &s, &c);
  EST[(d * 2 + 0) * BATCH + b] = c;
  EST[(d * 2 + 1) * BATCH + b] = s;
}

// ---- one-time: initial partial sims from EST ----
__global__ __launch_bounds__(256) void k_sims0(float* __restrict__ ws) {
  const ushort* T1  = (const ushort*)ws;
  const float*  EST = ws + EST_OFF;
  __half* P = (__half*)(ws + P_OFF);
  const int t  = threadIdx.x;
  const int ds = blockIdx.x;
  const int r0 = ds * 32;
  const int k4 = t * 4;

  float4 acc[BATCH];
  #pragma unroll
  for (int b = 0; b < BATCH; ++b) acc[b] = make_float4(0.f, 0.f, 0.f, 0.f);

  #pragma unroll 8
  for (int r = 0; r < 32; ++r) {
    const int row = r0 + r;
    const ushort4 tu = *(const ushort4*)&T1[(size_t)row * KCODES + k4];
    const float4 tv = make_float4(bf2f(tu.x), bf2f(tu.y), bf2f(tu.z), bf2f(tu.w));
    const float4 e0 = *(const float4*)&EST[row * BATCH + 0];
    const float4 e1 = *(const float4*)&EST[row * BATCH + 4];
    const float ev[8] = {e0.x, e0.y, e0.z, e0.w, e1.x, e1.y, e1.z, e1.w};
    #pragma unroll
    for (int b = 0; b < BATCH; ++b) {
      acc[b].x = fmaf(ev[b], tv.x, acc[b].x);
      acc[b].y = fmaf(ev[b], tv.y, acc[b].y);
      acc[b].z = fmaf(ev[b], tv.z, acc[b].z);
      acc[b].w = fmaf(ev[b], tv.w, acc[b].w);
    }
  }
  #pragma unroll
  for (int b = 0; b < BATCH; ++b) {
    __half* pp = &P[(size_t)ds * (BATCH * KCODES) + b * KCODES + k4];
    *(__half2*)(pp + 0) = __floats2half2_rn(acc[b].x, acc[b].y);
    *(__half2*)(pp + 2) = __floats2half2_rn(acc[b].z, acc[b].w);
  }
}

// ---- per-iter 1: W = exp2(c2 * sum of 256 partials) (unnormalized) ----
__global__ __launch_bounds__(64) void k_wexp(float* __restrict__ ws,
                                             const int* __restrict__ nit_p,
                                             int it) {
  if (it >= *nit_p) return;
  const __half2* P2 = (const __half2*)(ws + P_OFF);
  float* W = ws + W_OFF;
  const int g = blockIdx.x * 64 + threadIdx.x;   // pair index 0..4095
  float sx = 0.f, sy = 0.f;
  #pragma unroll 8
  for (int ds = 0; ds < NSLICE; ++ds) {
    const float2 v = __half22float2(P2[(size_t)ds * 4096 + g]);
    sx += v.x; sy += v.y;
  }
  const float c2 = 0.00244140625f * 1.4426950408889634f;  // (10/4096)*log2(e)
  float2 w; w.x = exp2f(sx * c2); w.y = exp2f(sy * c2);
  *(float2*)&W[2 * g] = w;
}

// ---- per-iter 2: step GEMM + est normalize (LDS) + NEXT partial sims ----
__global__ __launch_bounds__(256) void k_fused(float* __restrict__ ws,
                                               const int* __restrict__ nit_p,
                                               int it) {
  if (it >= *nit_p) return;
  const ushort* T1 = (const ushort*)ws;
  const float*  W  = ws + W_OFF;
  __half* P = (__half*)(ws + P_OFF);

  __shared__ float wl[BATCH * KCODES];   // 32 KB
  __shared__ float red2[32 * BATCH];     // [row_local][b]; raw -> normalized est

  const int t = threadIdx.x;
  #pragma unroll
  for (int j = 0; j < 8; ++j)
    *(float4*)&wl[(j * 256 + t) * 4] = *(const float4*)&W[(j * 256 + t) * 4];
  __syncthreads();

  const int wave = t >> 6, lane = t & 63;
  const int r0 = blockIdx.x * 32;        // block's 32 T1 rows (16 dims)
  const int rw = r0 + wave * 8;          // wave's 8 rows

  // phase 1: re/im = W . T1 rows
  float acc[8][BATCH];
  #pragma unroll
  for (int r = 0; r < 8; ++r)
    #pragma unroll
    for (int b = 0; b < BATCH; ++b) acc[r][b] = 0.f;

  #pragma unroll
  for (int c = 0; c < 4; ++c) {
    const int kk = c * 256 + lane * 4;
    float4 wr[BATCH];
    #pragma unroll
    for (int b = 0; b < BATCH; ++b)
      wr[b] = *(const float4*)&wl[b * KCODES + kk];
    #pragma unroll
    for (int r = 0; r < 8; ++r) {
      const ushort4 tu = *(const ushort4*)&T1[(size_t)(rw + r) * KCODES + kk];
      const float4 tv = make_float4(bf2f(tu.x), bf2f(tu.y), bf2f(tu.z), bf2f(tu.w));
      #pragma unroll
      for (int b = 0; b < BATCH; ++b) {
        acc[r][b] = fmaf(wr[b].x, tv.x, acc[r][b]);
        acc[r][b] = fmaf(wr[b].y, tv.y, acc[r][b]);
        acc[r][b] = fmaf(wr[b].z, tv.z, acc[r][b]);
        acc[r][b] = fmaf(wr[b].w, tv.w, acc[r][b]);
      }
    }
  }
  #pragma unroll
  for (int r = 0; r < 8; ++r)
    #pragma unroll
    for (int b = 0; b < BATCH; ++b) {
      const float s = wave_sum64(acc[r][b]);
      if (lane == 63) red2[(wave * 8 + r) * BATCH + b] = s;
    }
  __syncthreads();

  // normalize: est rows (cos,sin) = (re,im)/|z| ; in-place in LDS
  if (t < 128) {
    const int dl = t >> 3, b = t & 7;    // 16 dims x 8 batches
    const float re = red2[(2 * dl + 0) * BATCH + b];
    const float im = red2[(2 * dl + 1) * BATCH + b];
    const float n2 = fmaf(re, re, im * im);
    float ec, es;
    if (n2 > 0.f) {
      const float inv = rsqrtf(n2);
      ec = re * inv; es = im * inv;
    } else { ec = 1.f; es = 0.f; }       // atan2(0,0) = 0
    red2[(2 * dl + 0) * BATCH + b] = ec;
    red2[(2 * dl + 1) * BATCH + b] = es;
  }
  __syncthreads();

  // phase 2: this slice's partial sims for the NEXT iteration (T1 rows L2-hot)
  const int k4 = t * 4;
  float4 a2[BATCH];
  #pragma unroll
  for (int b = 0; b < BATCH; ++b) a2[b] = make_float4(0.f, 0.f, 0.f, 0.f);

  #pragma unroll 8
  for (int r = 0; r < 32; ++r) {
    const ushort4 tu = *(const ushort4*)&T1[(size_t)(r0 + r) * KCODES + k4];
    const float4 tv = make_float4(bf2f(tu.x), bf2f(tu.y), bf2f(tu.z), bf2f(tu.w));
    const float4 e0 = *(const float4*)&red2[r * BATCH + 0];
    const float4 e1 = *(const float4*)&red2[r * BATCH + 4];
    const float ev[8] = {e0.x, e0.y, e0.z, e0.w, e1.x, e1.y, e1.z, e1.w};
    #pragma unroll
    for (int b = 0; b < BATCH; ++b) {
      a2[b].x = fmaf(ev[b], tv.x, a2[b].x);
      a2[b].y = fmaf(ev[b], tv.y, a2[b].y);
      a2[b].z = fmaf(ev[b], tv.z, a2[b].z);
      a2[b].w = fmaf(ev[b], tv.w, a2[b].w);
    }
  }
  #pragma unroll
  for (int b = 0; b < BATCH; ++b) {
    __half* pp = &P[(size_t)blockIdx.x * (BATCH * KCODES) + b * KCODES + k4];
    *(__half2*)(pp + 0) = __floats2half2_rn(a2[b].x, a2[b].y);
    *(__half2*)(pp + 2) = __floats2half2_rn(a2[b].z, a2[b].w);
  }
}

// ---- epilogue: out = (sum of 256 partials) / DIMS ----
__global__ __launch_bounds__(64) void k_out(const float* __restrict__ ws,
                                            float* __restrict__ out) {
  const __half2* P2 = (const __half2*)(ws + P_OFF);
  const int g = blockIdx.x * 64 + threadIdx.x;   // pair index 0..4095
  float sx = 0.f, sy = 0.f;
  #pragma unroll 8
  for (int ds = 0; ds < NSLICE; ++ds) {
    const float2 v = __half22float2(P2[(size_t)ds * 4096 + g]);
    sx += v.x; sy += v.y;
  }
  const float sc = 1.0f / (float)DIMS;
  float2 o; o.x = sx * sc; o.y = sy * sc;
  *(float2*)&out[2 * g] = o;
}

extern "C" void kernel_launch(void* const* d_in, const int* in_sizes, int n_in,
                              void* d_out, int out_size, void* d_ws, size_t ws_size,
                              hipStream_t stream) {
  const float* sup = (const float*)d_in[0];
  const float* cbk = (const float*)d_in[1];
  const int*   nit = (const int*)d_in[2];
  float* outp = (float*)d_out;
  float* ws   = (float*)d_ws;

  hipLaunchKernelGGL(k_trig,  dim3(1024), dim3(256), 0, stream, cbk, ws);
  hipLaunchKernelGGL(k_init,  dim3(128),  dim3(256), 0, stream, sup, ws);
  hipLaunchKernelGGL(k_sims0, dim3(256),  dim3(256), 0, stream, ws);

  for (int it = 0; it < NITER_MAX; ++it) {
    hipLaunchKernelGGL(k_wexp,  dim3(64),  dim3(64),  0, stream, ws, nit, it);
    hipLaunchKernelGGL(k_fused, dim3(256), dim3(256), 0, stream, ws, nit, it);
  }
  hipLaunchKernelGGL(k_out, dim3(64), dim3(64), 0, stream, ws, outp);
}